// Round 7
// baseline (163.081 us; speedup 1.0000x reference)
//
#include <hip/hip_runtime.h>
#include <math.h>

// Output = segment_softmax over logits that depend ONLY on the inputs part of
// combined @ W_k: the agg(segment-mean MLP) contribution is constant within a
// segment and cancels exactly in the segment softmax (shift invariance).
// wx[h][d] = sum_j Wk[d, h*64+j]*Wq[h,j] / 8;  logit[n,h] = x[n,:].wx[h,:];
// per-segment softmax; out[h*N + n].
//
// Round 10: 2-kernel pipeline.
//  R6 confirmed decoupling (our kernels < fill kernels; ~45us of kernel time
//  left vs ~20us traffic ideal). This round removes the structural waste:
//   - prep fused into the logits kernel: boundary scan rides the x stream;
//     wx re-folded PER BLOCK from Wk/Wq (41KB L2-resident reads/block,
//     ~2.3us aggregate at 34.5TB/s L2) -> one fewer launch, one fewer 2MB
//     pass, no cross-kernel wx dependency.
//   - logits packed [n] as float4: kernel A 1x16B store/row; kernel B 1x16B
//     load/row (was 4 scattered plane loads).
//   - kernel B: online softmax (lane-local running max + rescaled sum)
//     merges passes 1+2; LDS cache is float4[512] (b128, ~12cyc vs 4x5.8).

#define NROWS 500000
#define DIM 40
#define NQ (DIM / 4)     // 10 float4 per row
#define NSEG 2048
#define DOTD 64
#define NH 4
#define ABLOCK 256
#define CROWS 512        // LDS cache rows (stat max segment len ~300)

// ---- kernel A: per-block wx fold + boundary scan + logits ----
__global__ __launch_bounds__(ABLOCK) void fused_logits_kernel(
    const float* __restrict__ x,        // [N, 40]
    const int* __restrict__ seg,        // [N], sorted
    const float* __restrict__ Wk,       // [168, 256]
    const float* __restrict__ Wq,       // [4, 64]
    int* __restrict__ seg_start,        // [NSEG]
    int* __restrict__ seg_end,          // [NSEG]
    float4* __restrict__ logit4)        // [NROWS]
{
    __shared__ __align__(16) float wxl[NH][DIM];   // 640 B

    const int tid = (int)threadIdx.x;

    // per-block wx fold (Wk x-part: 40KB, L2-resident; Wq: 1KB, L1)
    if (tid < DIM * NH) {
        const int h = tid & 3;          // adjacent threads: same d, h=0..3 ->
        const int d = tid >> 2;         // wave covers 16 consecutive Wk rows
        const float4* wkp = (const float4*)(Wk + d * (NH * DOTD) + h * DOTD);
        const float4* wqp = (const float4*)(Wq + h * DOTD);
        float acc = 0.f;
        #pragma unroll
        for (int j = 0; j < DOTD / 4; ++j) {
            const float4 a = wkp[j];
            const float4 b = wqp[j];
            acc += a.x * b.x + a.y * b.y + a.z * b.z + a.w * b.w;
        }
        wxl[h][d] = acc * 0.125f;       // fold 1/sqrt(64)
    }
    __syncthreads();

    const int n = (int)(blockIdx.x * ABLOCK + tid);
    if (n >= NROWS) return;             // after the only barrier

    // boundary scan with gap fill for empty segments (stat-never long)
    const int s = seg[n];
    if (n == 0) {
        seg_start[s] = 0;
        for (int t = 0; t < s; ++t) { seg_start[t] = 0; seg_end[t] = 0; }
    } else {
        const int sp = seg[n - 1];
        if (sp != s) {
            seg_start[s] = n;
            seg_end[sp] = n;
            for (int t = sp + 1; t < s; ++t) { seg_start[t] = n; seg_end[t] = n; }
        }
    }
    if (n == NROWS - 1) {
        seg_end[s] = NROWS;
        for (int t = s + 1; t < NSEG; ++t) { seg_start[t] = NROWS; seg_end[t] = NROWS; }
    }

    // logits: row-sequential x read (160 B/thread), one float4 store
    const float4* xr = (const float4*)(x + (size_t)n * DIM);
    float a[NH] = {0.f, 0.f, 0.f, 0.f};
    #pragma unroll
    for (int q = 0; q < NQ; ++q) {
        const float4 v = xr[q];
        #pragma unroll
        for (int h = 0; h < NH; ++h) {
            const float4 w = ((const float4*)wxl[h])[q];   // LDS broadcast
            a[h] += v.x * w.x + v.y * w.y + v.z * w.z + v.w * w.w;
        }
    }
    logit4[n] = make_float4(a[0], a[1], a[2], a[3]);
}

// ---- kernel B: per-segment online softmax over packed logits ----
// One wave per segment; LDS cache is strictly per-lane -> no barriers.
__global__ __launch_bounds__(64) void seg_softmax_kernel(
    const float4* __restrict__ logit4,  // [NROWS]
    const int* __restrict__ seg_start,
    const int* __restrict__ seg_end,
    float* __restrict__ out)            // [4, N]
{
    __shared__ __align__(16) float4 cache4[CROWS];   // 8 KB raw-logit cache

    const int lane = (int)threadIdx.x;
    const int s = (int)blockIdx.x;
    const int start = seg_start[s];
    const int rows = seg_end[s] - start;
    if (rows <= 0) return;

    // ---- pass 1: load (coalesced float4) + lane-local online max/sum ----
    float ml[NH], sl[NH];
    #pragma unroll
    for (int h = 0; h < NH; ++h) { ml[h] = -3.0e38f; sl[h] = 0.f; }

    for (int i = lane; i < rows; i += 64) {
        const float4 l4 = logit4[start + i];
        if (i < CROWS) cache4[i] = l4;               // b128, conflict-free
        const float l[NH] = {l4.x, l4.y, l4.z, l4.w};
        #pragma unroll
        for (int h = 0; h < NH; ++h) {
            const float nm = fmaxf(ml[h], l[h]);
            // branchless online: exp(ml-nm)=1 when max unchanged
            sl[h] = sl[h] * __expf(ml[h] - nm) + __expf(l[h] - nm);
            ml[h] = nm;
        }
    }

    // ---- wave combine: M = max ml; S = sum sl * exp(ml - M) ----
    float m[NH], rden[NH];
    #pragma unroll
    for (int h = 0; h < NH; ++h) {
        float M = ml[h];
        #pragma unroll
        for (int off = 32; off > 0; off >>= 1) M = fmaxf(M, __shfl_xor(M, off, 64));
        float S = sl[h] * __expf(ml[h] - M);         // idle lanes: 0 * 0 = 0
        #pragma unroll
        for (int off = 32; off > 0; off >>= 1) S += __shfl_xor(S, off, 64);
        m[h] = M;
        rden[h] = 1.0f / S;
    }

    // ---- pass 2: out = exp(l - m) * rden (coalesced per h plane) ----
    for (int i = lane; i < rows; i += 64) {
        const float4 l4 = (i < CROWS) ? cache4[i] : logit4[start + i];
        const float l[NH] = {l4.x, l4.y, l4.z, l4.w};
        const int n = start + i;
        #pragma unroll
        for (int h = 0; h < NH; ++h)
            out[(size_t)h * NROWS + n] = __expf(l[h] - m[h]) * rden[h];
    }
}

extern "C" void kernel_launch(void* const* d_in, const int* in_sizes, int n_in,
                              void* d_out, int out_size, void* d_ws, size_t ws_size,
                              hipStream_t stream) {
    const float* x  = (const float*)d_in[0];
    const int* seg  = (const int*)d_in[1];
    const float* Wk = (const float*)d_in[11];
    const float* Wq = (const float*)d_in[12];
    float* out = (float*)d_out;

    int* seg_start = (int*)d_ws;                           // [NSEG]
    int* seg_end   = seg_start + NSEG;                     // [NSEG]
    float4* logit4 = (float4*)((char*)d_ws + 16384);       // 16B-aligned, 8 MB

    const int nblk = (NROWS + ABLOCK - 1) / ABLOCK;
    hipLaunchKernelGGL(fused_logits_kernel, dim3(nblk), dim3(ABLOCK),
                       0, stream, x, seg, Wk, Wq, seg_start, seg_end, logit4);
    hipLaunchKernelGGL(seg_softmax_kernel, dim3(NSEG), dim3(64),
                       0, stream, logit4, seg_start, seg_end, out);
}